// Round 9
// baseline (400.055 us; speedup 1.0000x reference)
//
#include <hip/hip_runtime.h>

// 1D Euler, Roe flux + Harten entropy fix, 32 steps. Round 9:
// REGISTER-PERSISTENT state, 256 blocks x 1024 threads, with a 3-tier
// launch guard (occupancy-gated; bounded downside = round-8 kernel).
//
// Round-8 counters: WRITE_SIZE 396 MB (= full 12.4 MB state write leaving
// L2 every step; ping-pong working set 6 MB/XCD > 4 MiB L2) and ~6 us/step
// of non-VALU time (L2 store/load path + 1024-way barrier). Fix:
//  - Variant A (new): thread owns 4 cells in VGPRs for all 32 steps.
//    Neighbor cells via LDS (6 st + 6 ld /thread/step, WAR fenced);
//    block edges via relaxed SYSTEM-scope IC halo; dt via per-wave
//    atomicMax into 64 banked slots/step. Global state traffic: inputs
//    read once, d_out written once. Barrier: 256 arrivals, 16x16 tree.
//  - Variant B: round-8 kernel VERBATIM (proven 307 us) if A can't launch.
//  - Variant C: 33 plain dispatches of the same step_core if coop fails.

#define NXC   1048576
#define GAM   1.4f
#define GM1   0.4f
#define IGM1  2.5f
#define CFLC  0.5f
#define DXC   1e-3f
#define EFIX  0.1f
#define NSTEPS 32
#define NSLOT  (NSTEPS + 1)
#define SLOTW  64
#define BSTRIDE 32             // 128 B between barrier counters

// Variant A geometry
#define ABLK  1024
#define ACPT  4
#define ATILE (ABLK*ACPT)      // 4096
#define ANBLK (NXC/ATILE)      // 256 blocks = 1/CU

// Variant B/C geometry (round 8, proven)
#define BLK   256
#define CPT   4
#define TILE  (BLK*CPT)        // 1024
#define NBLK  (NXC/TILE)       // 1024

__device__ __forceinline__ float frcp(float x){ return __builtin_amdgcn_rcpf(x); }
__device__ __forceinline__ float frsq(float x){ return __builtin_amdgcn_rsqf(x); }
__device__ __forceinline__ float fsqrt_(float x){ return __builtin_amdgcn_sqrtf(x); }

__device__ __forceinline__ float sysloadf(const float* p) {
    return __hip_atomic_load(p, __ATOMIC_RELAXED, __HIP_MEMORY_SCOPE_SYSTEM);
}
__device__ __forceinline__ void sysstoref(float* p, float v) {
    __hip_atomic_store(p, v, __ATOMIC_RELAXED, __HIP_MEMORY_SCOPE_SYSTEM);
}
__device__ __forceinline__ unsigned sysloadu(const unsigned* p) {
    return __hip_atomic_load(p, __ATOMIC_RELAXED, __HIP_MEMORY_SCOPE_SYSTEM);
}
__device__ __forceinline__ void sysmaxu(unsigned* p, unsigned v) {
    __hip_atomic_fetch_max(p, v, __ATOMIC_RELAXED, __HIP_MEMORY_SCOPE_SYSTEM);
}

__device__ __forceinline__ float wave_max(float v) {
    #pragma unroll
    for (int k = 32; k >= 1; k >>= 1)
        v = fmaxf(v, __shfl_xor(v, k));
    return v;
}

// Relaxed system-scope two-level barrier (proven r4/7/8), parametrized
// fan-in. gen strictly increasing from 1. L1N/PERL1/L2N powers of two.
template<int L1N, int PERL1, int L2N>
__device__ __forceinline__ void gbar(unsigned* bar, int bid, unsigned gen) {
    unsigned* bar1 = bar;
    unsigned* bar2 = bar + 64 * BSTRIDE;              // L2 counter slot
    unsigned* flag = bar + 65 * BSTRIDE;              // generation flag
    __syncthreads();   // every wave drains vmcnt(0) before arriving
    if (threadIdx.x == 0) {
        unsigned o = __hip_atomic_fetch_add(
            &bar1[(bid & (L1N - 1)) * BSTRIDE], 1u,
            __ATOMIC_RELAXED, __HIP_MEMORY_SCOPE_SYSTEM);
        if ((o & (unsigned)(PERL1 - 1)) == (unsigned)(PERL1 - 1)) {
            unsigned o2 = __hip_atomic_fetch_add(
                bar2, 1u, __ATOMIC_RELAXED, __HIP_MEMORY_SCOPE_SYSTEM);
            if ((o2 & (unsigned)(L2N - 1)) == (unsigned)(L2N - 1))
                __hip_atomic_store(flag, gen, __ATOMIC_RELAXED,
                                   __HIP_MEMORY_SCOPE_SYSTEM);
        }
        while (__hip_atomic_load(flag, __ATOMIC_RELAXED,
                                 __HIP_MEMORY_SCOPE_SYSTEM) < gen)
            __builtin_amdgcn_s_sleep(2);
    }
    __syncthreads();
}

__global__ void ws_zero(unsigned* z) {
    const int n = 66 * BSTRIDE + NSLOT * SLOTW + NSLOT;
    for (int i = threadIdx.x; i < n; i += 256) z[i] = 0u;
}

// ---------------- shared Roe flux ----------------
__device__ __forceinline__ void roe5(const float rr[6], const float uu[6],
                                     const float pp[6], const float ss[6],
                                     const float gg[6],
                                     float Fr[5], float Fm[5], float Fe[5]) {
    #pragma unroll
    for (int j = 0; j < 5; ++j) {
        float sL = ss[j], sR = ss[j + 1];
        float uL = uu[j], uR = uu[j + 1];
        float invden = frcp(sL + sR);
        float ur = (sL * uL + sR * uR) * invden;
        float Hr = (gg[j] + gg[j + 1]) * invden;
        float c  = fsqrt_(fmaxf(GM1 * (Hr - 0.5f * ur * ur), 1e-10f));
        float eps = EFIX * c;
        float l1 = ur - c, l3 = ur + c;
        float a1 = fsqrt_(l1 * l1 + eps * eps);
        float a2 = fsqrt_(ur * ur + eps * eps);
        float a3 = fsqrt_(l3 * l3 + eps * eps);
        float drho = rr[j + 1] - rr[j];
        float du   = uR - uL;
        float dp   = pp[j + 1] - pp[j];
        float c2 = c * c;
        float inv2c2 = frcp(c2 + c2);
        float al2 = drho - (dp + dp) * inv2c2;
        float tcd = c * rr[j + 1] * du;
        float al1 = (dp - tcd) * inv2c2;
        float al3 = (dp + tcd) * inv2c2;
        float FrL = rr[j] * uL, FrR = rr[j + 1] * uR;
        float FmL = FrL * uL + pp[j], FmR = FrR * uR + pp[j + 1];
        float FeL = uL * (gg[j] * sL), FeR = uR * (gg[j + 1] * sR);
        float w1 = a1 * al1, w2 = a2 * al2, w3 = a3 * al3;
        Fr[j] = 0.5f * (FrL + FrR - (w1 + w2 + w3));
        Fm[j] = 0.5f * (FmL + FmR - (w1 * l1 + w2 * ur + w3 * l3));
        Fe[j] = 0.5f * (FeL + FeR - (w1 * (Hr - ur * c) + w2 * (0.5f * ur * ur)
                                     + w3 * (Hr + ur * c)));
    }
}

// ================= Variant A: register-persistent =================
__global__ __launch_bounds__(ABLK, 4) void euler_regs(
        const float* __restrict__ rho0, const float* __restrict__ u0,
        const float* __restrict__ p0, const float* __restrict__ tf,
        float* __restrict__ out, unsigned* __restrict__ slots,
        float* __restrict__ halo, unsigned* __restrict__ bar) {
    __shared__ float Lr[ABLK], Lu[ABLK], Lp[ABLK];  // each thread's cell3
    __shared__ float Rr[ABLK], Ru[ABLK], Rp[ABLK];  // each thread's cell0
    const int tid = threadIdx.x, bid = blockIdx.x;
    const int c0 = bid * ATILE + ACPT * tid;
    const int lane = tid & 63;
    unsigned gen = 0;

    float cr[4], cu[4], cp[4];

    // ---- prepass: inputs -> regs; LDS + halo(state0, parity0); amax row0
    {
        float4 r4 = *(const float4*)(rho0 + c0);
        float4 u4 = *(const float4*)(u0 + c0);
        float4 p4 = *(const float4*)(p0 + c0);
        cr[0]=r4.x; cr[1]=r4.y; cr[2]=r4.z; cr[3]=r4.w;
        cu[0]=u4.x; cu[1]=u4.y; cu[2]=u4.z; cu[3]=u4.w;
        cp[0]=p4.x; cp[1]=p4.y; cp[2]=p4.z; cp[3]=p4.w;
        float nm = 0.f;
        #pragma unroll
        for (int c = 0; c < 4; ++c)
            nm = fmaxf(nm, fabsf(cu[c]) + fsqrt_(GAM * cp[c] * frcp(cr[c])));
        Lr[tid]=cr[3]; Lu[tid]=cu[3]; Lp[tid]=cp[3];
        Rr[tid]=cr[0]; Ru[tid]=cu[0]; Rp[tid]=cp[0];
        if (tid == 0) {
            float* h = halo + (size_t)bid * 6;
            sysstoref(h, cr[0]); sysstoref(h+1, cu[0]); sysstoref(h+2, cp[0]);
        }
        if (tid == ABLK - 1) {
            float* h = halo + (size_t)bid * 6 + 3;
            sysstoref(h, cr[3]); sysstoref(h+1, cu[3]); sysstoref(h+2, cp[3]);
        }
        nm = wave_max(nm);
        if (lane == 0)
            sysmaxu(&slots[(size_t)(bid & (SLOTW - 1))], __float_as_uint(nm));
    }
    float t = 0.f;
    const float tfin = *tf;
    gbar<16, 16, 16>(bar, bid, ++gen);

    for (int k = 0; k < NSTEPS; ++k) {
        const int pk = k & 1;
        const float* hin  = halo + (size_t)pk * (ANBLK * 6);
        float*       hout = halo + (size_t)(1 - pk) * (ANBLK * 6);

        // dt slot load first (hide IC latency under compute)
        float av = __uint_as_float(
            sysloadu(&slots[(size_t)k * SLOTW + lane]));

        // neighbor cells: LDS (in-block) or IC halo (block edge)
        float rr[6], uu[6], pp[6];
        if (tid == 0) {
            if (bid > 0) {
                const float* h = hin + (size_t)(bid - 1) * 6 + 3;
                rr[0]=sysloadf(h); uu[0]=sysloadf(h+1); pp[0]=sysloadf(h+2);
            } else { rr[0]=cr[0]; uu[0]=cu[0]; pp[0]=cp[0]; }
        } else { rr[0]=Lr[tid-1]; uu[0]=Lu[tid-1]; pp[0]=Lp[tid-1]; }
        if (tid == ABLK - 1) {
            if (bid < ANBLK - 1) {
                const float* h = hin + (size_t)(bid + 1) * 6;
                rr[5]=sysloadf(h); uu[5]=sysloadf(h+1); pp[5]=sysloadf(h+2);
            } else { rr[5]=cr[3]; uu[5]=cu[3]; pp[5]=cp[3]; }
        } else { rr[5]=Rr[tid+1]; uu[5]=Ru[tid+1]; pp[5]=Rp[tid+1]; }
        #pragma unroll
        for (int c = 0; c < 4; ++c) { rr[c+1]=cr[c]; uu[c+1]=cu[c]; pp[c+1]=cp[c]; }

        // per-cell precompute, 5 fluxes
        float ss[6], gg[6];
        #pragma unroll
        for (int i = 0; i < 6; ++i) {
            float E = pp[i] * IGM1 + 0.5f * rr[i] * uu[i] * uu[i];
            float q = frsq(rr[i]);
            ss[i] = rr[i] * q;
            gg[i] = (E + pp[i]) * q;
        }
        float Fr[5], Fm[5], Fe[5];
        roe5(rr, uu, pp, ss, gg, Fr, Fm, Fe);

        float amax = wave_max(av);
        float dt = fminf(CFLC * DXC / amax, fmaxf(tfin - t, 0.f));
        t += dt;
        float dtdx = dt / DXC;

        // update 4 cells in registers
        float nm = 0.f;
        #pragma unroll
        for (int i = 1; i <= 4; ++i) {
            float E  = gg[i] * ss[i] - pp[i];          // (E+p) - p
            float r2 = rr[i]         - dtdx * (Fr[i] - Fr[i-1]);
            float m2 = rr[i] * uu[i] - dtdx * (Fm[i] - Fm[i-1]);
            float E2 = E             - dtdx * (Fe[i] - Fe[i-1]);
            float q2 = frsq(r2);
            float ir = q2 * q2;
            float u2 = m2 * ir;
            float p2 = GM1 * (E2 - 0.5f * r2 * u2 * u2);
            cr[i-1]=r2; cu[i-1]=u2; cp[i-1]=p2;
            nm = fmaxf(nm, fabsf(u2) + fsqrt_(GAM * p2 * ir));
        }

        if (k < NSTEPS - 1) {
            // WAR fence: all step-k LDS neighbor READS done before rewrite
            __syncthreads();
            Lr[tid]=cr[3]; Lu[tid]=cu[3]; Lp[tid]=cp[3];
            Rr[tid]=cr[0]; Ru[tid]=cu[0]; Rp[tid]=cp[0];
            if (tid == 0) {
                float* h = hout + (size_t)bid * 6;
                sysstoref(h, cr[0]); sysstoref(h+1, cu[0]); sysstoref(h+2, cp[0]);
            }
            if (tid == ABLK - 1) {
                float* h = hout + (size_t)bid * 6 + 3;
                sysstoref(h, cr[3]); sysstoref(h+1, cu[3]); sysstoref(h+2, cp[3]);
            }
            nm = wave_max(nm);
            if (lane == 0)
                sysmaxu(&slots[(size_t)(k + 1) * SLOTW + (bid & (SLOTW - 1))],
                        __float_as_uint(nm));
            gbar<16, 16, 16>(bar, bid, ++gen);   // entry sync drains stores
        } else {
            *(float4*)(out + c0)           = make_float4(cr[0], cr[1], cr[2], cr[3]);
            *(float4*)(out + NXC + c0)     = make_float4(cu[0], cu[1], cu[2], cu[3]);
            *(float4*)(out + 2*NXC + c0)   = make_float4(cp[0], cp[1], cp[2], cp[3]);
        }
    }
}

// ================= Variant B/C: round-8 reload design (proven) =========
__device__ __forceinline__ void prepass_core(
        const float* __restrict__ rho0, const float* __restrict__ u0,
        const float* __restrict__ p0, unsigned* __restrict__ slots,
        float* __restrict__ red) {
    const int tid = threadIdx.x, bid = blockIdx.x;
    const int c0 = bid * TILE + CPT * tid;
    float4 r4 = *(const float4*)(rho0 + c0);
    float4 u4 = *(const float4*)(u0 + c0);
    float4 p4 = *(const float4*)(p0 + c0);
    const float ra[4] = {r4.x, r4.y, r4.z, r4.w};
    const float ua[4] = {u4.x, u4.y, u4.z, u4.w};
    const float pa[4] = {p4.x, p4.y, p4.z, p4.w};
    float nm = 0.f;
    #pragma unroll
    for (int c = 0; c < CPT; ++c)
        nm = fmaxf(nm, fabsf(ua[c]) + fsqrt_(GAM * pa[c] * frcp(ra[c])));
    nm = wave_max(nm);
    if ((tid & 63) == 0) red[tid >> 6] = nm;
    __syncthreads();
    if (tid == 0)
        sysmaxu(&slots[(size_t)(bid & (SLOTW - 1))],
                __float_as_uint(fmaxf(fmaxf(red[0], red[1]),
                                      fmaxf(red[2], red[3]))));
}

__device__ __forceinline__ float step_core(
        int k, int bid, int tid,
        const float* __restrict__ rs, const float* __restrict__ us,
        const float* __restrict__ ps, float* __restrict__ dst,
        const float* __restrict__ hin, float* __restrict__ hout,
        unsigned* __restrict__ slots, float t, float tfin,
        float* __restrict__ red) {
    const int c0 = bid * TILE + CPT * tid;
    float av = __uint_as_float(
        sysloadu(&slots[(size_t)k * SLOTW + (tid & (SLOTW - 1))]));
    float rr[6], uu[6], pp[6];
    {
        float4 r4 = *(const float4*)(rs + c0);
        float4 u4 = *(const float4*)(us + c0);
        float4 p4 = *(const float4*)(ps + c0);
        rr[1]=r4.x; rr[2]=r4.y; rr[3]=r4.z; rr[4]=r4.w;
        uu[1]=u4.x; uu[2]=u4.y; uu[3]=u4.z; uu[4]=u4.w;
        pp[1]=p4.x; pp[2]=p4.y; pp[3]=p4.z; pp[4]=p4.w;
    }
    if (k > 0 && tid == 0 && bid > 0) {
        const float* h = hin + (size_t)(bid - 1) * 6 + 3;
        rr[0]=sysloadf(h); uu[0]=sysloadf(h+1); pp[0]=sysloadf(h+2);
    } else {
        int g = max(c0 - 1, 0);
        rr[0]=rs[g]; uu[0]=us[g]; pp[0]=ps[g];
    }
    if (k > 0 && tid == BLK - 1 && bid < NBLK - 1) {
        const float* h = hin + (size_t)(bid + 1) * 6;
        rr[5]=sysloadf(h); uu[5]=sysloadf(h+1); pp[5]=sysloadf(h+2);
    } else {
        int g = min(c0 + CPT, NXC - 1);
        rr[5]=rs[g]; uu[5]=us[g]; pp[5]=ps[g];
    }
    float ss[6], gg[6];
    #pragma unroll
    for (int i = 0; i < 6; ++i) {
        float E = pp[i] * IGM1 + 0.5f * rr[i] * uu[i] * uu[i];
        float q = frsq(rr[i]);
        ss[i] = rr[i] * q;
        gg[i] = (E + pp[i]) * q;
    }
    float Fr[5], Fm[5], Fe[5];
    roe5(rr, uu, pp, ss, gg, Fr, Fm, Fe);
    float amax = wave_max(av);
    float dt = fminf(CFLC * DXC / amax, fmaxf(tfin - t, 0.f));
    float dtdx = dt / DXC;
    float o_r[4], o_u[4], o_p[4];
    float nm = 0.f;
    #pragma unroll
    for (int i = 1; i <= 4; ++i) {
        float E  = gg[i] * ss[i] - pp[i];
        float r2 = rr[i]         - dtdx * (Fr[i] - Fr[i-1]);
        float m2 = rr[i] * uu[i] - dtdx * (Fm[i] - Fm[i-1]);
        float E2 = E             - dtdx * (Fe[i] - Fe[i-1]);
        float q2 = frsq(r2);
        float ir = q2 * q2;
        float u2 = m2 * ir;
        float p2 = GM1 * (E2 - 0.5f * r2 * u2 * u2);
        o_r[i-1]=r2; o_u[i-1]=u2; o_p[i-1]=p2;
        nm = fmaxf(nm, fabsf(u2) + fsqrt_(GAM * p2 * ir));
    }
    *(float4*)(dst + c0)         = make_float4(o_r[0], o_r[1], o_r[2], o_r[3]);
    *(float4*)(dst + NXC + c0)   = make_float4(o_u[0], o_u[1], o_u[2], o_u[3]);
    *(float4*)(dst + 2*NXC + c0) = make_float4(o_p[0], o_p[1], o_p[2], o_p[3]);
    if (tid == 0) {
        float* h = hout + (size_t)bid * 6;
        sysstoref(h, o_r[0]); sysstoref(h+1, o_u[0]); sysstoref(h+2, o_p[0]);
    }
    if (tid == BLK - 1) {
        float* h = hout + (size_t)bid * 6 + 3;
        sysstoref(h, o_r[3]); sysstoref(h+1, o_u[3]); sysstoref(h+2, o_p[3]);
    }
    nm = wave_max(nm);
    if ((tid & 63) == 0) red[tid >> 6] = nm;
    __syncthreads();
    if (tid == 0)
        sysmaxu(&slots[(size_t)(k + 1) * SLOTW + (bid & (SLOTW - 1))],
                __float_as_uint(fmaxf(fmaxf(red[0], red[1]),
                                      fmaxf(red[2], red[3]))));
    return dt;
}

__global__ __launch_bounds__(BLK, 4) void euler_pers(
        const float* __restrict__ rho0, const float* __restrict__ u0,
        const float* __restrict__ p0, const float* __restrict__ tf,
        float* __restrict__ A, float* __restrict__ B,
        unsigned* __restrict__ slots, float* __restrict__ halo,
        unsigned* __restrict__ bar) {
    __shared__ float red[4];
    const int tid = threadIdx.x, bid = blockIdx.x;
    unsigned gen = 0;
    prepass_core(rho0, u0, p0, slots, red);
    float t = 0.f;
    const float tfin = *tf;
    gbar<64, 16, 64>(bar, bid, ++gen);
    for (int k = 0; k < NSTEPS; ++k) {
        const int pk = k & 1;
        const float *rs, *us, *ps;
        if (k == 0) { rs = rho0; us = u0; ps = p0; }
        else { const float* s = pk ? B : A; rs = s; us = s + NXC; ps = s + 2*NXC; }
        float* dst = pk ? A : B;
        const float* hin = halo + (size_t)pk * (NBLK * 6);
        float* hout = halo + (size_t)(1 - pk) * (NBLK * 6);
        float dt = step_core(k, bid, tid, rs, us, ps, dst, hin, hout,
                             slots, t, tfin, red);
        t += dt;
        if (k < NSTEPS - 1) gbar<64, 16, 64>(bar, bid, ++gen);
    }
}

__global__ __launch_bounds__(BLK) void prepass_k(
        const float* __restrict__ rho0, const float* __restrict__ u0,
        const float* __restrict__ p0, unsigned* __restrict__ slots) {
    __shared__ float red[4];
    prepass_core(rho0, u0, p0, slots, red);
}

__global__ __launch_bounds__(BLK) void step_k(
        int k, const float* __restrict__ rs, const float* __restrict__ us,
        const float* __restrict__ ps, float* __restrict__ dst,
        const float* __restrict__ hin, float* __restrict__ hout,
        unsigned* __restrict__ slots, const float* __restrict__ tf,
        float* __restrict__ tbuf) {
    __shared__ float red[4];
    float t = tbuf[k];
    float dt = step_core(k, blockIdx.x, threadIdx.x, rs, us, ps, dst,
                         hin, hout, slots, t, *tf, red);
    if (blockIdx.x == 0 && threadIdx.x == 0) tbuf[k + 1] = t + dt;
}

extern "C" void kernel_launch(void* const* d_in, const int* in_sizes, int n_in,
                              void* d_out, int out_size, void* d_ws, size_t ws_size,
                              hipStream_t stream) {
    const float* rho0 = (const float*)d_in[0];
    const float* u0   = (const float*)d_in[1];
    const float* p0   = (const float*)d_in[2];
    const float* tf   = (const float*)d_in[3];
    // d_in[4] = n_steps (fixed at 32)

    float* A        = (float*)d_out;
    float* B        = (float*)d_ws;                          // 3*NXC floats
    unsigned* bar   = (unsigned*)(B + (size_t)3 * NXC);      // 66*32 uints
    unsigned* slots = bar + 66 * BSTRIDE;                    // 33*64
    float* tbuf     = (float*)(slots + NSLOT * SLOTW);       // 33
    float* halo     = tbuf + NSLOT;                          // 2*NBLK*6 max

    ws_zero<<<1, 256, 0, stream>>>(bar);

    int dev = 0; (void)hipGetDevice(&dev);
    int cus = 0;
    (void)hipDeviceGetAttribute(&cus, hipDeviceAttributeMultiprocessorCount, dev);

    bool done = false;
    int occA = 0;
    (void)hipOccupancyMaxActiveBlocksPerMultiprocessor(&occA, euler_regs, ABLK, 0);
    if (occA > 0 && cus > 0 && (long)occA * cus >= ANBLK) {
        void* args[] = {(void*)&rho0, (void*)&u0, (void*)&p0, (void*)&tf,
                        (void*)&A, (void*)&slots, (void*)&halo, (void*)&bar};
        done = hipLaunchCooperativeKernel((void*)euler_regs, dim3(ANBLK),
                                          dim3(ABLK), args, 0, stream)
               == hipSuccess;
    }
    if (!done) {
        int occB = 0;
        (void)hipOccupancyMaxActiveBlocksPerMultiprocessor(&occB, euler_pers, BLK, 0);
        if (occB > 0 && cus > 0 && (long)occB * cus >= NBLK) {
            void* args[] = {(void*)&rho0, (void*)&u0, (void*)&p0, (void*)&tf,
                            (void*)&A, (void*)&B, (void*)&slots, (void*)&halo,
                            (void*)&bar};
            done = hipLaunchCooperativeKernel((void*)euler_pers, dim3(NBLK),
                                              dim3(BLK), args, 0, stream)
                   == hipSuccess;
        }
    }
    if (!done) {
        prepass_k<<<NBLK, BLK, 0, stream>>>(rho0, u0, p0, slots);
        for (int k = 0; k < NSTEPS; ++k) {
            const int pk = k & 1;
            const float *rs, *us, *ps;
            if (k == 0) { rs = rho0; us = u0; ps = p0; }
            else { const float* s = pk ? B : A; rs = s; us = s + NXC; ps = s + 2*NXC; }
            float* dst = pk ? A : B;
            const float* hin = halo + (size_t)pk * (NBLK * 6);
            float* hout = halo + (size_t)(1 - pk) * (NBLK * 6);
            step_k<<<NBLK, BLK, 0, stream>>>(k, rs, us, ps, dst, hin, hout,
                                             slots, tf, tbuf);
        }
    }
}